// Round 10
// baseline (284.435 us; speedup 1.0000x reference)
//
#include <hip/hip_runtime.h>

typedef unsigned short ushortT;
typedef unsigned short ushort8 __attribute__((ext_vector_type(8)));
typedef unsigned short ushort4v __attribute__((ext_vector_type(4)));
typedef short short8 __attribute__((ext_vector_type(8)));
typedef float floatx4 __attribute__((ext_vector_type(4)));

#define DEVINL __device__ __forceinline__

static DEVINL ushortT f2bf(float f) {
  union { float f; unsigned u; } v; v.f = f;
  unsigned u = v.u + 0x7FFFu + ((v.u >> 16) & 1u);
  return (ushortT)(u >> 16);
}
static DEVINL float bf2f(ushortT h) {
  union { unsigned u; float f; } v; v.u = ((unsigned)h) << 16;
  return v.f;
}

#define GLOAD_LDS16(g, s) __builtin_amdgcn_global_load_lds( \
    (const __attribute__((address_space(1))) void*)(g),     \
    (__attribute__((address_space(3))) void*)(s), 16, 0, 0)

// dims: B=16, C=256, HID=512, NH=8, DH=64, N=4096
#define NB 16
#define CIN 256
#define HID 512
#define NPIX 4096

// ---------------- K0: convert weights to bf16 ----------------
__global__ __launch_bounds__(256) void k_convw(const float* __restrict__ wqkv,
                                               const float* __restrict__ wout,
                                               ushortT* __restrict__ wqkvb,
                                               ushortT* __restrict__ woutb) {
  int i = blockIdx.x * 256 + threadIdx.x;
  if (i < 1536 * 256) wqkvb[i] = f2bf(wqkv[i]);
  if (i < 256 * 512)  woutb[i] = f2bf(wout[i]);
}

// ---------------- K1: rmsnorm over channels, write xn transposed [b][p][c] bf16 ----------------
__global__ __launch_bounds__(256) void k_rms1(const float* __restrict__ x,
                                              const float* __restrict__ g1,
                                              ushortT* __restrict__ xnT) {
  int pid = blockIdx.x * 256 + threadIdx.x;   // 0..65535
  int b = pid >> 12, p = pid & 4095;
  const float* xb = x + (size_t)b * CIN * NPIX + p;
  float ss = 0.f;
  for (int c = 0; c < CIN; ++c) { float v = xb[(size_t)c * NPIX]; ss += v * v; }
  float nrm = sqrtf(ss);
  float sc = 16.0f / fmaxf(nrm, 1e-12f);
  ushortT* dst = xnT + (size_t)pid * CIN;
  for (int c0 = 0; c0 < CIN; c0 += 8) {
    ushort8 pack;
#pragma unroll
    for (int j = 0; j < 8; ++j) {
      int c = c0 + j;
      pack[j] = f2bf(xb[(size_t)c * NPIX] * sc * g1[c]);
    }
    *(ushort8*)(dst + c0) = pack;
  }
}

// ---------------- K2: qkv GEMM, BK=64 dbuf staging, swizzled LDS (r7-proven) ----------------
// NEW vs r7: XCD-aware bijective block swizzle (384 xy-blocks = 8 XCDs x 48):
// consecutive dispatch-order blocks on one XCD now share xnT panels in its L2.
// Everything else byte-identical to the passing r7 kernel.
__global__ __launch_bounds__(256) void k_qkv(const ushortT* __restrict__ wq,
                                             const ushortT* __restrict__ xnT,
                                             ushortT* __restrict__ qT,
                                             ushortT* __restrict__ kv) {
  int lin = blockIdx.x + (blockIdx.y << 5);   // 0..383  (32 bn x 12 bm)
  int swz = (lin & 7) * 48 + (lin >> 3);      // bijective: 384 = 8*48
  int bn = swz & 31;         // 0..31  (p tile of 128)
  int bm = swz >> 5;         // 0..11  (o tile of 128)
  int b  = blockIdx.z;
  int tid = threadIdx.x;
  int w = tid >> 6, l = tid & 63;
  int wm = w >> 1, wn = w & 1;
  int lane_r = l & 15, lane_g = l >> 4;
  int m0 = bm * 128, n0 = bn * 128;

  __shared__ __align__(16) ushortT smem[2][2][128 * 64];   // [buf][A/B], 64KB

  const ushortT* xb = xnT + (size_t)b * NPIX * CIN;

  int srow = tid >> 3;                            // 0..31 (row within 32-row group)
  int scol = ((tid & 7) ^ (srow & 7)) * 8;        // pre-swizzled source col
  const ushortT* gA0 = wq + (size_t)(m0 + srow) * CIN + scol;
  const ushortT* gB0 = xb + (size_t)(n0 + srow) * CIN + scol;
  int ldsrow = w * 8;                             // wave-uniform base row per instr

  floatx4 acc[4][4];
#pragma unroll
  for (int i = 0; i < 4; i++)
#pragma unroll
    for (int j = 0; j < 4; j++) acc[i][j] = (floatx4)0.f;

  // prologue: stage k-step 0 into buf 0
#pragma unroll
  for (int i = 0; i < 4; ++i)
    GLOAD_LDS16(gA0 + (size_t)(32 * i) * CIN, &smem[0][0][(ldsrow + 32 * i) * 64]);
#pragma unroll
  for (int i = 0; i < 4; ++i)
    GLOAD_LDS16(gB0 + (size_t)(32 * i) * CIN, &smem[0][1][(ldsrow + 32 * i) * 64]);
  __syncthreads();

  int buf = 0;
  for (int ks = 0; ks < 4; ++ks) {
    if (ks < 3) {
      int k0 = (ks + 1) * 64;
      int nb = buf ^ 1;
#pragma unroll
      for (int i = 0; i < 4; ++i)
        GLOAD_LDS16(gA0 + (size_t)(32 * i) * CIN + k0, &smem[nb][0][(ldsrow + 32 * i) * 64]);
#pragma unroll
      for (int i = 0; i < 4; ++i)
        GLOAD_LDS16(gB0 + (size_t)(32 * i) * CIN + k0, &smem[nb][1][(ldsrow + 32 * i) * 64]);
    }
#pragma unroll
    for (int kk = 0; kk < 2; ++kk) {
      int phys = (kk * 4 + lane_g) ^ (lane_r & 7);
      short8 a[4], bb[4];
#pragma unroll
      for (int mt = 0; mt < 4; ++mt) {
        int R = wm * 64 + mt * 16 + lane_r;
        a[mt] = *(const short8*)&smem[buf][0][R * 64 + phys * 8];
      }
#pragma unroll
      for (int nt = 0; nt < 4; ++nt) {
        int R = wn * 64 + nt * 16 + lane_r;
        bb[nt] = *(const short8*)&smem[buf][1][R * 64 + phys * 8];
      }
#pragma unroll
      for (int mt = 0; mt < 4; ++mt)
#pragma unroll
        for (int nt = 0; nt < 4; ++nt)
          acc[mt][nt] = __builtin_amdgcn_mfma_f32_16x16x32_bf16(a[mt], bb[nt], acc[mt][nt], 0, 0, 0);
    }
    if (ks < 3) __syncthreads();
    buf ^= 1;
  }

  int m0w = m0 + wm * 64, n0w = n0 + wn * 64;

  if (m0w < 512) {
    // ---- fused q softmax over d: wave's 64 rows are exactly one head ----
    float inv[4];
#pragma unroll
    for (int nt = 0; nt < 4; ++nt) {
      float mx = -1e30f;
#pragma unroll
      for (int mt = 0; mt < 4; ++mt)
#pragma unroll
        for (int r = 0; r < 4; ++r) mx = fmaxf(mx, acc[mt][nt][r]);
      mx = fmaxf(mx, __shfl_xor(mx, 16));
      mx = fmaxf(mx, __shfl_xor(mx, 32));
      float s = 0.f;
#pragma unroll
      for (int mt = 0; mt < 4; ++mt)
#pragma unroll
        for (int r = 0; r < 4; ++r) {
          float e = __expf(acc[mt][nt][r] - mx);
          acc[mt][nt][r] = e;
          s += e;
        }
      s += __shfl_xor(s, 16);
      s += __shfl_xor(s, 32);
      inv[nt] = 0.125f / s;    // SCALE = 1/8 folded in
    }
    ushortT* qb = qT + (size_t)b * NPIX * HID;
#pragma unroll
    for (int mt = 0; mt < 4; ++mt) {
      int o = m0w + mt * 16 + lane_g * 4;
#pragma unroll
      for (int nt = 0; nt < 4; ++nt) {
        int p = n0w + nt * 16 + lane_r;
        ushort4v pk;
#pragma unroll
        for (int r = 0; r < 4; ++r) pk[r] = f2bf(acc[mt][nt][r] * inv[nt]);
        *(ushort4v*)(qb + (size_t)p * HID + o) = pk;
      }
    }
  } else {          // k,v raw -> kv[ch][p], scalar stores (r3-proven path)
    ushortT* kvb = kv + (size_t)b * 1024 * NPIX;
    int mo = m0w - 512;
#pragma unroll
    for (int mt = 0; mt < 4; ++mt)
#pragma unroll
      for (int nt = 0; nt < 4; ++nt) {
        int p = n0w + nt * 16 + lane_r;
#pragma unroll
        for (int r = 0; r < 4; ++r) {
          int ch = mo + mt * 16 + lane_g * 4 + r;
          kvb[(size_t)ch * NPIX + p] = f2bf(acc[mt][nt][r]);
        }
      }
  }
}

// ---------------- K3a: k softmax over n (4096), in place, vectorized (r7-proven) ----------------
__global__ __launch_bounds__(256) void k_ksm(ushortT* __restrict__ kv) {
  int row = blockIdx.x;                // 0..8191
  int b = row >> 9, ch = row & 511;
  ushortT* ptr = kv + (size_t)(b * 1024 + ch) * NPIX;
  int tid = threadIdx.x;
  int w = tid >> 6, l = tid & 63;
  ushort8 r0 = *(ushort8*)(ptr + tid * 16);
  ushort8 r1 = *(ushort8*)(ptr + tid * 16 + 8);
  float v[16];
  float mx = -1e30f;
#pragma unroll
  for (int j = 0; j < 8; ++j) { v[j] = bf2f(r0[j]); v[8 + j] = bf2f(r1[j]); }
#pragma unroll
  for (int j = 0; j < 16; ++j) mx = fmaxf(mx, v[j]);
  for (int off = 32; off; off >>= 1) mx = fmaxf(mx, __shfl_xor(mx, off));
  __shared__ float smax[4], ssum[4];
  if (l == 0) smax[w] = mx;
  __syncthreads();
  mx = fmaxf(fmaxf(smax[0], smax[1]), fmaxf(smax[2], smax[3]));
  float s = 0.f;
#pragma unroll
  for (int j = 0; j < 16; ++j) { v[j] = __expf(v[j] - mx); s += v[j]; }
  for (int off = 32; off; off >>= 1) s += __shfl_xor(s, off);
  if (l == 0) ssum[w] = s;
  __syncthreads();
  s = ssum[0] + ssum[1] + ssum[2] + ssum[3];
  float inv = 1.0f / s;
  ushort8 o0, o1;
#pragma unroll
  for (int j = 0; j < 8; ++j) { o0[j] = f2bf(v[j] * inv); o1[j] = f2bf(v[8 + j] * inv); }
  *(ushort8*)(ptr + tid * 16) = o0;
  *(ushort8*)(ptr + tid * 16 + 8) = o1;
}

// ---------------- K4: partial context over n-segment, staged LDS (r7-proven) ----------------
__global__ __launch_bounds__(256) void k_ctx(const ushortT* __restrict__ kv,
                                             float* __restrict__ ctxp) {
  int blk = blockIdx.x;   // 0..511
  int bh = blk >> 2, ns = blk & 3;
  int b = bh >> 3, h = bh & 7;
  int tid = threadIdx.x, w = tid >> 6, l = tid & 63;
  int lane_r = l & 15, lane_g = l >> 4;
  const ushortT* kb = kv + ((size_t)b * 1024 + h * 64) * NPIX + ns * 1024;
  const ushortT* vb = kv + ((size_t)b * 1024 + 512 + h * 64) * NPIX + ns * 1024;

  __shared__ __align__(16) ushortT smem[4][64 * 128];   // 64KB: [0..1]=K bufs, [2..3]=V bufs

  int srow = tid >> 4;                    // 0..15
  int soff = ((tid & 15) ^ srow) * 8;     // pre-swizzled source col (elems)
  int wofs = w * 512;                     // per-wave LDS base within a 4KB op
  int cbase = (w * 4 + lane_g);           // this wave's logical chunk id

  floatx4 acc[4][4];
#pragma unroll
  for (int i = 0; i < 4; i++)
#pragma unroll
    for (int j = 0; j < 4; j++) acc[i][j] = (floatx4)0.f;

  // prologue stage step 0 into buf 0
#pragma unroll
  for (int i = 0; i < 4; ++i)
    GLOAD_LDS16(kb + (size_t)(srow + 16 * i) * NPIX + soff, &smem[0][i * 2048 + wofs]);
#pragma unroll
  for (int i = 0; i < 4; ++i)
    GLOAD_LDS16(vb + (size_t)(srow + 16 * i) * NPIX + soff, &smem[2][i * 2048 + wofs]);
  __syncthreads();

  int buf = 0;
  for (int st = 0; st < 8; ++st) {
    if (st < 7) {
      int nb0 = (st + 1) * 128;
      int nb = buf ^ 1;
#pragma unroll
      for (int i = 0; i < 4; ++i)
        GLOAD_LDS16(kb + (size_t)(srow + 16 * i) * NPIX + nb0 + soff, &smem[nb][i * 2048 + wofs]);
#pragma unroll
      for (int i = 0; i < 4; ++i)
        GLOAD_LDS16(vb + (size_t)(srow + 16 * i) * NPIX + nb0 + soff, &smem[2 + nb][i * 2048 + wofs]);
    }
    short8 a[4], bb[4];
#pragma unroll
    for (int mt = 0; mt < 4; ++mt) {
      int R = mt * 16 + lane_r;
      a[mt] = *(const short8*)&smem[buf][R * 128 + (cbase ^ lane_r) * 8];
    }
#pragma unroll
    for (int nt = 0; nt < 4; ++nt) {
      int R = nt * 16 + lane_r;
      bb[nt] = *(const short8*)&smem[2 + buf][R * 128 + (cbase ^ lane_r) * 8];
    }
#pragma unroll
    for (int mt = 0; mt < 4; ++mt)
#pragma unroll
      for (int nt = 0; nt < 4; ++nt)
        acc[mt][nt] = __builtin_amdgcn_mfma_f32_16x16x32_bf16(a[mt], bb[nt], acc[mt][nt], 0, 0, 0);
    if (st < 7) __syncthreads();
    buf ^= 1;
  }

  // cross-wave reduction, aliasing the (now dead) staging LDS
  __syncthreads();
  float* red = (float*)&smem[0][0];       // [4][64][64] f32 = 64KB
#pragma unroll
  for (int mt = 0; mt < 4; ++mt)
#pragma unroll
    for (int nt = 0; nt < 4; ++nt)
#pragma unroll
      for (int r = 0; r < 4; ++r)
        red[(w * 64 + mt * 16 + lane_g * 4 + r) * 64 + nt * 16 + lane_r] = acc[mt][nt][r];
  __syncthreads();
  float* cb = ctxp + (size_t)blk * 4096;
  int base = tid * 16;
#pragma unroll
  for (int j = 0; j < 16; ++j) {
    int idx = base + j;
    cb[idx] = red[idx] + red[4096 + idx] + red[8192 + idx] + red[12288 + idx];
  }
}

// ---------------- K4b: sum 4 n-segment partials -> ctx bf16 ----------------
__global__ __launch_bounds__(256) void k_ctxsum(const float* __restrict__ ctxp,
                                                ushortT* __restrict__ ctx) {
  int i = blockIdx.x * 256 + threadIdx.x;   // < 524288
  int bh = i >> 12, j = i & 4095;
  const float* p = ctxp + (size_t)bh * 4 * 4096 + j;
  ctx[i] = f2bf(p[0] + p[4096] + p[8192] + p[12288]);
}

// ---------------- K5: Weff[b][o][h*64+d] = sum_e Wout[o][h*64+e] * ctx[b,h,d,e] ----------------
__global__ __launch_bounds__(256) void k_weff(const ushortT* __restrict__ woutb,
                                              const ushortT* __restrict__ ctx,
                                              ushortT* __restrict__ weff) {
  int bh = blockIdx.x; int b = bh >> 3, h = bh & 7;
  int tid = threadIdx.x, w = tid >> 6, l = tid & 63;
  int lane_r = l & 15, lane_g = l >> 4;
  const ushortT* cb = ctx + (size_t)bh * 64 * 64;

  floatx4 acc[4][4];
#pragma unroll
  for (int i = 0; i < 4; i++)
#pragma unroll
    for (int j = 0; j < 4; j++) acc[i][j] = (floatx4)0.f;

#pragma unroll
  for (int ks = 0; ks < 2; ++ks) {
    int k0 = ks * 32 + lane_g * 8;
    short8 a[4], bb[4];
#pragma unroll
    for (int mt = 0; mt < 4; ++mt)
      a[mt] = *(const short8*)(woutb + (size_t)(w * 64 + mt * 16 + lane_r) * HID + h * 64 + k0);
#pragma unroll
    for (int nt = 0; nt < 4; ++nt)
      bb[nt] = *(const short8*)(cb + (size_t)(nt * 16 + lane_r) * 64 + k0);
#pragma unroll
    for (int mt = 0; mt < 4; ++mt)
#pragma unroll
      for (int nt = 0; nt < 4; ++nt)
        acc[mt][nt] = __builtin_amdgcn_mfma_f32_16x16x32_bf16(a[mt], bb[nt], acc[mt][nt], 0, 0, 0);
  }
  ushortT* wb = weff + (size_t)b * 256 * 512;
#pragma unroll
  for (int mt = 0; mt < 4; ++mt)
#pragma unroll
    for (int nt = 0; nt < 4; ++nt)
#pragma unroll
      for (int r = 0; r < 4; ++r) {
        int o = w * 64 + mt * 16 + lane_g * 4 + r;
        int d = nt * 16 + lane_r;
        wb[(size_t)o * 512 + h * 64 + d] = f2bf(acc[mt][nt][r]);
      }
}

// ---------------- K6: out = Weff[b] @ qT[b]^T, staged LDS, + bias, fused rmsnorm ----------------
__global__ __launch_bounds__(256) void k_out(const ushortT* __restrict__ weff,
                                             const ushortT* __restrict__ qT,
                                             const float* __restrict__ bout,
                                             const float* __restrict__ g2,
                                             float* __restrict__ out) {
  int bn = blockIdx.x;   // 0..63 (p tile of 64)
  int b  = blockIdx.y;
  int tid = threadIdx.x, w = tid >> 6, l = tid & 63;
  int lane_r = l & 15, lane_g = l >> 4;
  const ushortT* wb = weff + (size_t)b * 256 * 512;
  const ushortT* qb = qT + (size_t)b * NPIX * HID;
  int n0 = bn * 64;

  __shared__ ushortT As[2][256 * 32];   // 16KB per buf
  __shared__ ushortT Bq[2][64 * 32];    // 4KB per buf

  int srow = tid >> 2;                                // 0..63
  int scol = ((tid & 3) ^ ((tid >> 3) & 3)) * 8;
  const ushortT* gA0 = wb + (size_t)srow * HID + scol;
  const ushortT* gB0 = qb + (size_t)(n0 + srow) * HID + scol;
  int wofs = w * 512;
  int rq = (lane_r >> 1) & 3;

  floatx4 acc[4][4];
#pragma unroll
  for (int i = 0; i < 4; i++)
#pragma unroll
    for (int j = 0; j < 4; j++) acc[i][j] = (floatx4)0.f;

  // prologue
#pragma unroll
  for (int i = 0; i < 4; ++i)
    GLOAD_LDS16(gA0 + (size_t)(64 * i) * HID, &As[0][i * 2048 + wofs]);
  GLOAD_LDS16(gB0, &Bq[0][wofs]);
  __syncthreads();

  int buf = 0;
  for (int ks = 0; ks < 16; ++ks) {
    if (ks < 15) {
      int k0 = (ks + 1) * 32;
      int nb = buf ^ 1;
#pragma unroll
      for (int i = 0; i < 4; ++i)
        GLOAD_LDS16(gA0 + (size_t)(64 * i) * HID + k0, &As[nb][i * 2048 + wofs]);
      GLOAD_LDS16(gB0 + k0, &Bq[nb][wofs]);
    }
    short8 a[4], bb[4];
#pragma unroll
    for (int mt = 0; mt < 4; ++mt) {
      int R = w * 64 + mt * 16 + lane_r;
      a[mt] = *(const short8*)&As[buf][R * 32 + (lane_g ^ rq) * 8];
    }
#pragma unroll
    for (int nt = 0; nt < 4; ++nt) {
      int R = nt * 16 + lane_r;
      bb[nt] = *(const short8*)&Bq[buf][R * 32 + (lane_g ^ rq) * 8];
    }
#pragma unroll
    for (int mt = 0; mt < 4; ++mt)
#pragma unroll
      for (int nt = 0; nt < 4; ++nt)
        acc[mt][nt] = __builtin_amdgcn_mfma_f32_16x16x32_bf16(a[mt], bb[nt], acc[mt][nt], 0, 0, 0);
    if (ks < 15) __syncthreads();
    buf ^= 1;
  }

  float colsq[4] = {0.f, 0.f, 0.f, 0.f};
#pragma unroll
  for (int mt = 0; mt < 4; ++mt)
#pragma unroll
    for (int r = 0; r < 4; ++r) {
      int o = w * 64 + mt * 16 + lane_g * 4 + r;
      float bo = bout[o];
#pragma unroll
      for (int nt = 0; nt < 4; ++nt) {
        float t = acc[mt][nt][r] + bo;
        acc[mt][nt][r] = t;
        colsq[nt] += t * t;
      }
    }
#pragma unroll
  for (int nt = 0; nt < 4; ++nt) {
    colsq[nt] += __shfl_xor(colsq[nt], 16);
    colsq[nt] += __shfl_xor(colsq[nt], 32);
  }
  __shared__ float cred[4][64];
  if (l < 16) {
#pragma unroll
    for (int nt = 0; nt < 4; ++nt) cred[w][nt * 16 + l] = colsq[nt];
  }
  __syncthreads();
  float inv[4];
#pragma unroll
  for (int nt = 0; nt < 4; ++nt) {
    int col = nt * 16 + lane_r;
    float s = cred[0][col] + cred[1][col] + cred[2][col] + cred[3][col];
    float nrm = sqrtf(s);
    inv[nt] = 16.0f / fmaxf(nrm, 1e-12f);
  }
  float* ob = out + (size_t)b * 256 * NPIX;
#pragma unroll
  for (int mt = 0; mt < 4; ++mt)
#pragma unroll
    for (int r = 0; r < 4; ++r) {
      int o = w * 64 + mt * 16 + lane_g * 4 + r;
      float g = g2[o];
#pragma unroll
      for (int nt = 0; nt < 4; ++nt) {
        int p = n0 + nt * 16 + lane_r;
        ob[(size_t)o * NPIX + p] = acc[mt][nt][r] * inv[nt] * g;
      }
    }
}

extern "C" void kernel_launch(void* const* d_in, const int* in_sizes, int n_in,
                              void* d_out, int out_size, void* d_ws, size_t ws_size,
                              hipStream_t stream) {
  const float* x    = (const float*)d_in[0];
  const float* g1   = (const float*)d_in[1];
  const float* wqkv = (const float*)d_in[2];
  const float* wout = (const float*)d_in[3];
  const float* bout = (const float*)d_in[4];
  const float* g2   = (const float*)d_in[5];
  float* out = (float*)d_out;
  char* ws = (char*)d_ws;

  // workspace layout (bytes)
  ushortT* xnT   = (ushortT*)(ws);                       // 16*4096*256*2  = 33554432
  ushortT* kv    = (ushortT*)(ws + 33554432);            // 16*1024*4096*2 = 134217728
  ushortT* qT    = (ushortT*)(ws + 167772160);           // 16*4096*512*2  = 67108864
  ushortT* ctx   = (ushortT*)(ws + 234881024);           // 16*8*64*64*2   = 131072
  ushortT* weff  = (ushortT*)(ws + 235012096);           // 16*256*512*2   = 4194304
  ushortT* wqkvb = (ushortT*)(ws + 239206400);           // 1536*256*2     = 786432
  ushortT* woutb = (ushortT*)(ws + 239992832);           // 256*512*2      = 262144
  float*   ctxp  = (float*)(ws);                         // 8MB, reuses dead xnT region

  hipLaunchKernelGGL(k_convw,  dim3(1536), dim3(256), 0, stream, wqkv, wout, wqkvb, woutb);
  hipLaunchKernelGGL(k_rms1,   dim3(256),  dim3(256), 0, stream, x, g1, xnT);
  hipLaunchKernelGGL(k_qkv,    dim3(32, 12, 16), dim3(256), 0, stream, wqkvb, xnT, qT, kv);
  hipLaunchKernelGGL(k_ksm,    dim3(8192), dim3(256), 0, stream, kv);
  hipLaunchKernelGGL(k_ctx,    dim3(512),  dim3(256), 0, stream, kv, ctxp);
  hipLaunchKernelGGL(k_ctxsum, dim3(2048), dim3(256), 0, stream, ctxp, ctx);
  hipLaunchKernelGGL(k_weff,   dim3(128),  dim3(256), 0, stream, woutb, ctx, weff);
  hipLaunchKernelGGL(k_out,    dim3(64, 16), dim3(256), 0, stream, weff, qT, bout, g2, out);
}

// Round 11
// 216.518 us; speedup vs baseline: 1.3137x; 1.3137x over previous
//
#include <hip/hip_runtime.h>

typedef unsigned short ushortT;
typedef unsigned short ushort8 __attribute__((ext_vector_type(8)));
typedef unsigned short ushort4v __attribute__((ext_vector_type(4)));
typedef short short8 __attribute__((ext_vector_type(8)));
typedef float floatx4 __attribute__((ext_vector_type(4)));

#define DEVINL __device__ __forceinline__

static DEVINL ushortT f2bf(float f) {
  union { float f; unsigned u; } v; v.f = f;
  unsigned u = v.u + 0x7FFFu + ((v.u >> 16) & 1u);
  return (ushortT)(u >> 16);
}
static DEVINL float bf2f(ushortT h) {
  union { unsigned u; float f; } v; v.u = ((unsigned)h) << 16;
  return v.f;
}

#define GLOAD_LDS16(g, s) __builtin_amdgcn_global_load_lds( \
    (const __attribute__((address_space(1))) void*)(g),     \
    (__attribute__((address_space(3))) void*)(s), 16, 0, 0)

// dims: B=16, C=256, HID=512, NH=8, DH=64, N=4096
#define NB 16
#define CIN 256
#define HID 512
#define NPIX 4096

// ---------------- K0: convert weights to bf16 ----------------
__global__ __launch_bounds__(256) void k_convw(const float* __restrict__ wqkv,
                                               const float* __restrict__ wout,
                                               ushortT* __restrict__ wqkvb,
                                               ushortT* __restrict__ woutb) {
  int i = blockIdx.x * 256 + threadIdx.x;
  if (i < 1536 * 256) wqkvb[i] = f2bf(wqkv[i]);
  if (i < 256 * 512)  woutb[i] = f2bf(wout[i]);
}

// ---------------- K1: rmsnorm, single x read via LDS tile ----------------
// Block = 32 pixels x 256 channels staged in LDS f32 (32KB). x read ONCE
// (old version read it twice: sumsq pass + write pass).
__global__ __launch_bounds__(256) void k_rms1(const float* __restrict__ x,
                                              const float* __restrict__ g1,
                                              ushortT* __restrict__ xnT) {
  int blk = blockIdx.x;              // 0..2047
  int b = blk >> 7, p0 = (blk & 127) * 32;
  int tid = threadIdx.x;
  __shared__ float lx[256 * 32];     // [c][p], 32KB
  __shared__ float ssp[256];
  __shared__ float scs[32];

  // stage: 8 channels x 32 pixels per iteration, coalesced 128B rows
  {
    int c8 = tid >> 5, p = tid & 31;
    const float* xb = x + (size_t)b * CIN * NPIX + p0 + p;
#pragma unroll
    for (int c0 = 0; c0 < 256; c0 += 8) {
      int c = c0 + c8;
      lx[c * 32 + p] = xb[(size_t)c * NPIX];
    }
  }
  __syncthreads();

  // per-pixel sum of squares: 8 groups of 32 channels (2-way LDS alias = free)
  {
    int p = tid & 31, g = tid >> 5;
    float s = 0.f;
#pragma unroll
    for (int cc = 0; cc < 32; ++cc) {
      float v = lx[(g * 32 + cc) * 32 + p];
      s += v * v;
    }
    ssp[tid] = s;
  }
  __syncthreads();
  if (tid < 32) {
    float ss = 0.f;
#pragma unroll
    for (int g = 0; g < 8; ++g) ss += ssp[tid + g * 32];
    scs[tid] = 16.0f / fmaxf(sqrtf(ss), 1e-12f);
  }
  __syncthreads();

  // scale + pack + write: thread owns pixel p=tid&31, channel chunk j=tid>>5
  {
    int p = tid & 31, j = tid >> 5;
    float scp = scs[p];
    ushortT* dst = xnT + (size_t)(b * NPIX + p0 + p) * CIN + j * 32;
#pragma unroll
    for (int q = 0; q < 4; ++q) {
      ushort8 pk;
#pragma unroll
      for (int e = 0; e < 8; ++e) {
        int c = j * 32 + q * 8 + e;
        pk[e] = f2bf(lx[c * 32 + p] * scp * g1[c]);
      }
      *(ushort8*)(dst + q * 8) = pk;
    }
  }
}

// ---------------- K2: qkv GEMM, BK=64 dbuf staging, swizzled LDS (r7 exact) ----------------
// Default dispatch order is already XCD-optimal here (bn%8 = XCD affinity,
// 4 xnT panels/XCD reused across all bm) — r10's swizzle was a 7x FETCH regression.
__global__ __launch_bounds__(256) void k_qkv(const ushortT* __restrict__ wq,
                                             const ushortT* __restrict__ xnT,
                                             ushortT* __restrict__ qT,
                                             ushortT* __restrict__ kv) {
  int bn = blockIdx.x;       // 0..31  (p tile of 128)
  int bm = blockIdx.y;       // 0..11  (o tile of 128)
  int b  = blockIdx.z;
  int tid = threadIdx.x;
  int w = tid >> 6, l = tid & 63;
  int wm = w >> 1, wn = w & 1;
  int lane_r = l & 15, lane_g = l >> 4;
  int m0 = bm * 128, n0 = bn * 128;

  __shared__ __align__(16) ushortT smem[2][2][128 * 64];   // [buf][A/B], 64KB

  const ushortT* xb = xnT + (size_t)b * NPIX * CIN;

  int srow = tid >> 3;                            // 0..31 (row within 32-row group)
  int scol = ((tid & 7) ^ (srow & 7)) * 8;        // pre-swizzled source col
  const ushortT* gA0 = wq + (size_t)(m0 + srow) * CIN + scol;
  const ushortT* gB0 = xb + (size_t)(n0 + srow) * CIN + scol;
  int ldsrow = w * 8;                             // wave-uniform base row per instr

  floatx4 acc[4][4];
#pragma unroll
  for (int i = 0; i < 4; i++)
#pragma unroll
    for (int j = 0; j < 4; j++) acc[i][j] = (floatx4)0.f;

  // prologue: stage k-step 0 into buf 0
#pragma unroll
  for (int i = 0; i < 4; ++i)
    GLOAD_LDS16(gA0 + (size_t)(32 * i) * CIN, &smem[0][0][(ldsrow + 32 * i) * 64]);
#pragma unroll
  for (int i = 0; i < 4; ++i)
    GLOAD_LDS16(gB0 + (size_t)(32 * i) * CIN, &smem[0][1][(ldsrow + 32 * i) * 64]);
  __syncthreads();

  int buf = 0;
  for (int ks = 0; ks < 4; ++ks) {
    if (ks < 3) {
      int k0 = (ks + 1) * 64;
      int nb = buf ^ 1;
#pragma unroll
      for (int i = 0; i < 4; ++i)
        GLOAD_LDS16(gA0 + (size_t)(32 * i) * CIN + k0, &smem[nb][0][(ldsrow + 32 * i) * 64]);
#pragma unroll
      for (int i = 0; i < 4; ++i)
        GLOAD_LDS16(gB0 + (size_t)(32 * i) * CIN + k0, &smem[nb][1][(ldsrow + 32 * i) * 64]);
    }
#pragma unroll
    for (int kk = 0; kk < 2; ++kk) {
      int phys = (kk * 4 + lane_g) ^ (lane_r & 7);
      short8 a[4], bb[4];
#pragma unroll
      for (int mt = 0; mt < 4; ++mt) {
        int R = wm * 64 + mt * 16 + lane_r;
        a[mt] = *(const short8*)&smem[buf][0][R * 64 + phys * 8];
      }
#pragma unroll
      for (int nt = 0; nt < 4; ++nt) {
        int R = wn * 64 + nt * 16 + lane_r;
        bb[nt] = *(const short8*)&smem[buf][1][R * 64 + phys * 8];
      }
#pragma unroll
      for (int mt = 0; mt < 4; ++mt)
#pragma unroll
        for (int nt = 0; nt < 4; ++nt)
          acc[mt][nt] = __builtin_amdgcn_mfma_f32_16x16x32_bf16(a[mt], bb[nt], acc[mt][nt], 0, 0, 0);
    }
    if (ks < 3) __syncthreads();
    buf ^= 1;
  }

  int m0w = m0 + wm * 64, n0w = n0 + wn * 64;

  if (m0w < 512) {
    // ---- fused q softmax over d: wave's 64 rows are exactly one head ----
    float inv[4];
#pragma unroll
    for (int nt = 0; nt < 4; ++nt) {
      float mx = -1e30f;
#pragma unroll
      for (int mt = 0; mt < 4; ++mt)
#pragma unroll
        for (int r = 0; r < 4; ++r) mx = fmaxf(mx, acc[mt][nt][r]);
      mx = fmaxf(mx, __shfl_xor(mx, 16));
      mx = fmaxf(mx, __shfl_xor(mx, 32));
      float s = 0.f;
#pragma unroll
      for (int mt = 0; mt < 4; ++mt)
#pragma unroll
        for (int r = 0; r < 4; ++r) {
          float e = __expf(acc[mt][nt][r] - mx);
          acc[mt][nt][r] = e;
          s += e;
        }
      s += __shfl_xor(s, 16);
      s += __shfl_xor(s, 32);
      inv[nt] = 0.125f / s;    // SCALE = 1/8 folded in
    }
    ushortT* qb = qT + (size_t)b * NPIX * HID;
#pragma unroll
    for (int mt = 0; mt < 4; ++mt) {
      int o = m0w + mt * 16 + lane_g * 4;
#pragma unroll
      for (int nt = 0; nt < 4; ++nt) {
        int p = n0w + nt * 16 + lane_r;
        ushort4v pk;
#pragma unroll
        for (int r = 0; r < 4; ++r) pk[r] = f2bf(acc[mt][nt][r] * inv[nt]);
        *(ushort4v*)(qb + (size_t)p * HID + o) = pk;
      }
    }
  } else {          // k,v raw -> kv[ch][p], scalar stores (r3-proven path)
    ushortT* kvb = kv + (size_t)b * 1024 * NPIX;
    int mo = m0w - 512;
#pragma unroll
    for (int mt = 0; mt < 4; ++mt)
#pragma unroll
      for (int nt = 0; nt < 4; ++nt) {
        int p = n0w + nt * 16 + lane_r;
#pragma unroll
        for (int r = 0; r < 4; ++r) {
          int ch = mo + mt * 16 + lane_g * 4 + r;
          kvb[(size_t)ch * NPIX + p] = f2bf(acc[mt][nt][r]);
        }
      }
  }
}

// ---------------- K3a: k softmax over n (4096), in place, vectorized (r7-proven) ----------------
__global__ __launch_bounds__(256) void k_ksm(ushortT* __restrict__ kv) {
  int row = blockIdx.x;                // 0..8191
  int b = row >> 9, ch = row & 511;
  ushortT* ptr = kv + (size_t)(b * 1024 + ch) * NPIX;
  int tid = threadIdx.x;
  int w = tid >> 6, l = tid & 63;
  ushort8 r0 = *(ushort8*)(ptr + tid * 16);
  ushort8 r1 = *(ushort8*)(ptr + tid * 16 + 8);
  float v[16];
  float mx = -1e30f;
#pragma unroll
  for (int j = 0; j < 8; ++j) { v[j] = bf2f(r0[j]); v[8 + j] = bf2f(r1[j]); }
#pragma unroll
  for (int j = 0; j < 16; ++j) mx = fmaxf(mx, v[j]);
  for (int off = 32; off; off >>= 1) mx = fmaxf(mx, __shfl_xor(mx, off));
  __shared__ float smax[4], ssum[4];
  if (l == 0) smax[w] = mx;
  __syncthreads();
  mx = fmaxf(fmaxf(smax[0], smax[1]), fmaxf(smax[2], smax[3]));
  float s = 0.f;
#pragma unroll
  for (int j = 0; j < 16; ++j) { v[j] = __expf(v[j] - mx); s += v[j]; }
  for (int off = 32; off; off >>= 1) s += __shfl_xor(s, off);
  if (l == 0) ssum[w] = s;
  __syncthreads();
  s = ssum[0] + ssum[1] + ssum[2] + ssum[3];
  float inv = 1.0f / s;
  ushort8 o0, o1;
#pragma unroll
  for (int j = 0; j < 8; ++j) { o0[j] = f2bf(v[j] * inv); o1[j] = f2bf(v[8 + j] * inv); }
  *(ushort8*)(ptr + tid * 16) = o0;
  *(ushort8*)(ptr + tid * 16 + 8) = o1;
}

// ---------------- K4: partial context over n-segment, staged LDS (r7-proven) ----------------
__global__ __launch_bounds__(256) void k_ctx(const ushortT* __restrict__ kv,
                                             float* __restrict__ ctxp) {
  int blk = blockIdx.x;   // 0..511
  int bh = blk >> 2, ns = blk & 3;
  int b = bh >> 3, h = bh & 7;
  int tid = threadIdx.x, w = tid >> 6, l = tid & 63;
  int lane_r = l & 15, lane_g = l >> 4;
  const ushortT* kb = kv + ((size_t)b * 1024 + h * 64) * NPIX + ns * 1024;
  const ushortT* vb = kv + ((size_t)b * 1024 + 512 + h * 64) * NPIX + ns * 1024;

  __shared__ __align__(16) ushortT smem[4][64 * 128];   // 64KB: [0..1]=K bufs, [2..3]=V bufs

  int srow = tid >> 4;                    // 0..15
  int soff = ((tid & 15) ^ srow) * 8;     // pre-swizzled source col (elems)
  int wofs = w * 512;                     // per-wave LDS base within a 4KB op
  int cbase = (w * 4 + lane_g);           // this wave's logical chunk id

  floatx4 acc[4][4];
#pragma unroll
  for (int i = 0; i < 4; i++)
#pragma unroll
    for (int j = 0; j < 4; j++) acc[i][j] = (floatx4)0.f;

  // prologue stage step 0 into buf 0
#pragma unroll
  for (int i = 0; i < 4; ++i)
    GLOAD_LDS16(kb + (size_t)(srow + 16 * i) * NPIX + soff, &smem[0][i * 2048 + wofs]);
#pragma unroll
  for (int i = 0; i < 4; ++i)
    GLOAD_LDS16(vb + (size_t)(srow + 16 * i) * NPIX + soff, &smem[2][i * 2048 + wofs]);
  __syncthreads();

  int buf = 0;
  for (int st = 0; st < 8; ++st) {
    if (st < 7) {
      int nb0 = (st + 1) * 128;
      int nb = buf ^ 1;
#pragma unroll
      for (int i = 0; i < 4; ++i)
        GLOAD_LDS16(kb + (size_t)(srow + 16 * i) * NPIX + nb0 + soff, &smem[nb][i * 2048 + wofs]);
#pragma unroll
      for (int i = 0; i < 4; ++i)
        GLOAD_LDS16(vb + (size_t)(srow + 16 * i) * NPIX + nb0 + soff, &smem[2 + nb][i * 2048 + wofs]);
    }
    short8 a[4], bb[4];
#pragma unroll
    for (int mt = 0; mt < 4; ++mt) {
      int R = mt * 16 + lane_r;
      a[mt] = *(const short8*)&smem[buf][R * 128 + (cbase ^ lane_r) * 8];
    }
#pragma unroll
    for (int nt = 0; nt < 4; ++nt) {
      int R = nt * 16 + lane_r;
      bb[nt] = *(const short8*)&smem[2 + buf][R * 128 + (cbase ^ lane_r) * 8];
    }
#pragma unroll
    for (int mt = 0; mt < 4; ++mt)
#pragma unroll
      for (int nt = 0; nt < 4; ++nt)
        acc[mt][nt] = __builtin_amdgcn_mfma_f32_16x16x32_bf16(a[mt], bb[nt], acc[mt][nt], 0, 0, 0);
    if (st < 7) __syncthreads();
    buf ^= 1;
  }

  // cross-wave reduction, aliasing the (now dead) staging LDS
  __syncthreads();
  float* red = (float*)&smem[0][0];       // [4][64][64] f32 = 64KB
#pragma unroll
  for (int mt = 0; mt < 4; ++mt)
#pragma unroll
    for (int nt = 0; nt < 4; ++nt)
#pragma unroll
      for (int r = 0; r < 4; ++r)
        red[(w * 64 + mt * 16 + lane_g * 4 + r) * 64 + nt * 16 + lane_r] = acc[mt][nt][r];
  __syncthreads();
  float* cb = ctxp + (size_t)blk * 4096;
  int base = tid * 16;
#pragma unroll
  for (int j = 0; j < 16; ++j) {
    int idx = base + j;
    cb[idx] = red[idx] + red[4096 + idx] + red[8192 + idx] + red[12288 + idx];
  }
}

// ---------------- K4b: sum 4 n-segment partials -> ctx bf16 ----------------
__global__ __launch_bounds__(256) void k_ctxsum(const float* __restrict__ ctxp,
                                                ushortT* __restrict__ ctx) {
  int i = blockIdx.x * 256 + threadIdx.x;   // < 524288
  int bh = i >> 12, j = i & 4095;
  const float* p = ctxp + (size_t)bh * 4 * 4096 + j;
  ctx[i] = f2bf(p[0] + p[4096] + p[8192] + p[12288]);
}

// ---------------- K5: Weff[b][o][h*64+d] = sum_e Wout[o][h*64+e] * ctx[b,h,d,e] ----------------
__global__ __launch_bounds__(256) void k_weff(const ushortT* __restrict__ woutb,
                                              const ushortT* __restrict__ ctx,
                                              ushortT* __restrict__ weff) {
  int bh = blockIdx.x; int b = bh >> 3, h = bh & 7;
  int tid = threadIdx.x, w = tid >> 6, l = tid & 63;
  int lane_r = l & 15, lane_g = l >> 4;
  const ushortT* cb = ctx + (size_t)bh * 64 * 64;

  floatx4 acc[4][4];
#pragma unroll
  for (int i = 0; i < 4; i++)
#pragma unroll
    for (int j = 0; j < 4; j++) acc[i][j] = (floatx4)0.f;

#pragma unroll
  for (int ks = 0; ks < 2; ++ks) {
    int k0 = ks * 32 + lane_g * 8;
    short8 a[4], bb[4];
#pragma unroll
    for (int mt = 0; mt < 4; ++mt)
      a[mt] = *(const short8*)(woutb + (size_t)(w * 64 + mt * 16 + lane_r) * HID + h * 64 + k0);
#pragma unroll
    for (int nt = 0; nt < 4; ++nt)
      bb[nt] = *(const short8*)(cb + (size_t)(nt * 16 + lane_r) * 64 + k0);
#pragma unroll
    for (int mt = 0; mt < 4; ++mt)
#pragma unroll
      for (int nt = 0; nt < 4; ++nt)
        acc[mt][nt] = __builtin_amdgcn_mfma_f32_16x16x32_bf16(a[mt], bb[nt], acc[mt][nt], 0, 0, 0);
  }
  ushortT* wb = weff + (size_t)b * 256 * 512;
#pragma unroll
  for (int mt = 0; mt < 4; ++mt)
#pragma unroll
    for (int nt = 0; nt < 4; ++nt)
#pragma unroll
      for (int r = 0; r < 4; ++r) {
        int o = w * 64 + mt * 16 + lane_g * 4 + r;
        int d = nt * 16 + lane_r;
        wb[(size_t)o * 512 + h * 64 + d] = f2bf(acc[mt][nt][r]);
      }
}

// ---------------- K6: out = Weff[b] @ qT[b]^T, staged LDS, + bias, fused rmsnorm ----------------
__global__ __launch_bounds__(256) void k_out(const ushortT* __restrict__ weff,
                                             const ushortT* __restrict__ qT,
                                             const float* __restrict__ bout,
                                             const float* __restrict__ g2,
                                             float* __restrict__ out) {
  int bn = blockIdx.x;   // 0..63 (p tile of 64)
  int b  = blockIdx.y;
  int tid = threadIdx.x, w = tid >> 6, l = tid & 63;
  int lane_r = l & 15, lane_g = l >> 4;
  const ushortT* wb = weff + (size_t)b * 256 * 512;
  const ushortT* qb = qT + (size_t)b * NPIX * HID;
  int n0 = bn * 64;

  __shared__ ushortT As[2][256 * 32];   // 16KB per buf
  __shared__ ushortT Bq[2][64 * 32];    // 4KB per buf

  int srow = tid >> 2;                                // 0..63
  int scol = ((tid & 3) ^ ((tid >> 3) & 3)) * 8;
  const ushortT* gA0 = wb + (size_t)srow * HID + scol;
  const ushortT* gB0 = qb + (size_t)(n0 + srow) * HID + scol;
  int wofs = w * 512;
  int rq = (lane_r >> 1) & 3;

  floatx4 acc[4][4];
#pragma unroll
  for (int i = 0; i < 4; i++)
#pragma unroll
    for (int j = 0; j < 4; j++) acc[i][j] = (floatx4)0.f;

  // prologue
#pragma unroll
  for (int i = 0; i < 4; ++i)
    GLOAD_LDS16(gA0 + (size_t)(64 * i) * HID, &As[0][i * 2048 + wofs]);
  GLOAD_LDS16(gB0, &Bq[0][wofs]);
  __syncthreads();

  int buf = 0;
  for (int ks = 0; ks < 16; ++ks) {
    if (ks < 15) {
      int k0 = (ks + 1) * 32;
      int nb = buf ^ 1;
#pragma unroll
      for (int i = 0; i < 4; ++i)
        GLOAD_LDS16(gA0 + (size_t)(64 * i) * HID + k0, &As[nb][i * 2048 + wofs]);
      GLOAD_LDS16(gB0 + k0, &Bq[nb][wofs]);
    }
    short8 a[4], bb[4];
#pragma unroll
    for (int mt = 0; mt < 4; ++mt) {
      int R = w * 64 + mt * 16 + lane_r;
      a[mt] = *(const short8*)&As[buf][R * 32 + (lane_g ^ rq) * 8];
    }
#pragma unroll
    for (int nt = 0; nt < 4; ++nt) {
      int R = nt * 16 + lane_r;
      bb[nt] = *(const short8*)&Bq[buf][R * 32 + (lane_g ^ rq) * 8];
    }
#pragma unroll
    for (int mt = 0; mt < 4; ++mt)
#pragma unroll
      for (int nt = 0; nt < 4; ++nt)
        acc[mt][nt] = __builtin_amdgcn_mfma_f32_16x16x32_bf16(a[mt], bb[nt], acc[mt][nt], 0, 0, 0);
    if (ks < 15) __syncthreads();
    buf ^= 1;
  }

  float colsq[4] = {0.f, 0.f, 0.f, 0.f};
#pragma unroll
  for (int mt = 0; mt < 4; ++mt)
#pragma unroll
    for (int r = 0; r < 4; ++r) {
      int o = w * 64 + mt * 16 + lane_g * 4 + r;
      float bo = bout[o];
#pragma unroll
      for (int nt = 0; nt < 4; ++nt) {
        float t = acc[mt][nt][r] + bo;
        acc[mt][nt][r] = t;
        colsq[nt] += t * t;
      }
    }
#pragma unroll
  for (int nt = 0; nt < 4; ++nt) {
    colsq[nt] += __shfl_xor(colsq[nt], 16);
    colsq[nt] += __shfl_xor(colsq[nt], 32);
  }
  __shared__ float cred[4][64];
  if (l < 16) {
#pragma unroll
    for (int nt = 0; nt < 4; ++nt) cred[w][nt * 16 + l] = colsq[nt];
  }
  __syncthreads();
  float inv[4];
#pragma unroll
  for (int nt = 0; nt < 4; ++nt) {
    int col = nt * 16 + lane_r;
    float s = cred[0][col] + cred[1][col] + cred[2][col] + cred[3][col];
    float nrm = sqrtf(s);
    inv[nt] = 16.0f / fmaxf(nrm, 1e-12f);
  }
  float* ob = out + (size_t)b * 256 * NPIX;
#pragma unroll
  for (int mt = 0; mt < 4; ++mt)
#pragma unroll
    for (int r = 0; r < 4; ++r) {
      int o = w * 64 + mt * 16 + lane_g * 4 + r;
      float g = g2[o];
#pragma unroll
      for (int nt = 0; nt < 4; ++nt) {
        int p = n0 + nt * 16 + lane_r;
        ob[(size_t)o * NPIX + p] = acc[mt][nt][r] * inv[nt] * g;
      }
    }
}

extern "C" void kernel_launch(void* const* d_in, const int* in_sizes, int n_in,
                              void* d_out, int out_size, void* d_ws, size_t ws_size,
                              hipStream_t stream) {
  const float* x    = (const float*)d_in[0];
  const float* g1   = (const float*)d_in[1];
  const float* wqkv = (const float*)d_in[2];
  const float* wout = (const float*)d_in[3];
  const float* bout = (const float*)d_in[4];
  const float* g2   = (const float*)d_in[5];
  float* out = (float*)d_out;
  char* ws = (char*)d_ws;

  // workspace layout (bytes)
  ushortT* xnT   = (ushortT*)(ws);                       // 16*4096*256*2  = 33554432
  ushortT* kv    = (ushortT*)(ws + 33554432);            // 16*1024*4096*2 = 134217728
  ushortT* qT    = (ushortT*)(ws + 167772160);           // 16*4096*512*2  = 67108864
  ushortT* ctx   = (ushortT*)(ws + 234881024);           // 16*8*64*64*2   = 131072
  ushortT* weff  = (ushortT*)(ws + 235012096);           // 16*256*512*2   = 4194304
  ushortT* wqkvb = (ushortT*)(ws + 239206400);           // 1536*256*2     = 786432
  ushortT* woutb = (ushortT*)(ws + 239992832);           // 256*512*2      = 262144
  float*   ctxp  = (float*)(ws);                         // 8MB, reuses dead xnT region

  hipLaunchKernelGGL(k_convw,  dim3(1536), dim3(256), 0, stream, wqkv, wout, wqkvb, woutb);
  hipLaunchKernelGGL(k_rms1,   dim3(2048), dim3(256), 0, stream, x, g1, xnT);
  hipLaunchKernelGGL(k_qkv,    dim3(32, 12, 16), dim3(256), 0, stream, wqkvb, xnT, qT, kv);
  hipLaunchKernelGGL(k_ksm,    dim3(8192), dim3(256), 0, stream, kv);
  hipLaunchKernelGGL(k_ctx,    dim3(512),  dim3(256), 0, stream, kv, ctxp);
  hipLaunchKernelGGL(k_ctxsum, dim3(2048), dim3(256), 0, stream, ctxp, ctx);
  hipLaunchKernelGGL(k_weff,   dim3(128),  dim3(256), 0, stream, woutb, ctx, weff);
  hipLaunchKernelGGL(k_out,    dim3(64, 16), dim3(256), 0, stream, weff, qT, bout, g2, out);
}